// Round 8
// baseline (1097.917 us; speedup 1.0000x reference)
//
#include <hip/hip_runtime.h>
#include <hip/hip_fp16.h>
#include <cmath>

#define BB 128
#define TT 365
#define DD 32
#define HH 512
#define G4H 2048  // 4*HH

// ws layout: buf0 fp16 at byte 0 (131072B used) | buf1 fp16 at byte 262144
//            bar at byte 524288 (16 groups x 32 uints = 512 uints used)
//            cst at float-ofs 131328 (fallback only, fp32)
// hipMemsetAsync zeroes [0, 787456) bytes each call (covers all of above).

typedef float f32x4 __attribute__((ext_vector_type(4)));
typedef _Float16 f16x8 __attribute__((ext_vector_type(8)));

__device__ __forceinline__ float sigf(float z) { return 1.f / (1.f + __expf(-z)); }

// fast tanh: (1-e)/(1+e) with e=exp(-2|x|), sign restored; e<=1 so no overflow
__device__ __forceinline__ float ftanh(float z) {
  float a = fabsf(z);
  float e = __expf(-2.f * a);
  float r = (1.f - e) / (1.f + e);
  return (z < 0.f) ? -r : r;
}

// ---------------------------------------------------------------------------
// Persistent kernel v9: tiling + EVERY coherence op class identical to v8
// (1086us, passed): 256 WGs x 512 thr, 16 batch groups x 8 rows x 16
// col-WGs, fp16 h exchange via agent-scope __hip_atomic_load/store, W held
// as MFMA B-fragments in VGPRs for all 365 steps. v8's counters: VALUBusy
// 20%, MfmaUtil 8%, HBM 2% -> ~70% of each 2.75us step is the serial
// latency chain (store-drain -> tid0 arrive/poll -> syncthreads -> h loads).
// v9 trims it: (1) per-wave poll (lane0 + shfl bcast) at loop TOP replaces
// tid0 poll + final syncthreads -- each wave issues its h loads the moment
// the count lands; (2) x-staging(t+1) + out store moved into the
// arrive->poll shadow; (3) MFMA chain split into 2 accumulators (acc0
// bias-initialized); (4) fast tanh in the epilogue. Syncs/step 4 -> 3.
// Visibility: producers drain (syncthreads waits vmcnt(0)) before the
// agent-scope arrive-add; consumer waves' agent-scope atomic h loads issue
// only after seeing the count -- v8's exact guarantee, per-wave.
// ---------------------------------------------------------------------------
__global__ __launch_bounds__(512, 2)
void lstm_persistent(const float* __restrict__ x,
                     const float* __restrict__ Wx,
                     const float* __restrict__ Wh,
                     const float* __restrict__ bias,
                     float* __restrict__ out,
                     float* __restrict__ hws) {
  __shared__ __align__(16) _Float16 WlH[128 * 552];  // 141312 B (init staging)
  __shared__ __align__(16) _Float16 AshH[8 * 552];   // 8832 B  [x(32)|h(512)]
  __shared__ __align__(16) float ZxS[8 * 128];       // 4096 B
  __shared__ __align__(16) float Cs[8][32];          // 1024 B
  __shared__ __align__(16) float BiasS[128];         // 512 B
  // total ~155.8 KB -> 1 WG/CU

  const int tid = threadIdx.x;
  const int lane = tid & 63;
  const int wv = tid >> 6;                 // wave id [0,8)
  const int fcol = wv * 16 + (lane & 15);  // output col [0,128)
  const int kq = lane >> 4;                // k-subgroup [0,4)
  const int arow = lane & 15;              // A-fragment row (valid if <8)
  const int wg = blockIdx.x;
  const int bb = wg & 15;                  // batch group [0,16), 8 rows
  const int nb = wg >> 4;                  // col-WG [0,16), 32 h-cols
  const int b0g = bb * 8;
  const int n0 = nb * 32;

  // ---- stage weights as fp16: lanes 0..31 read 32 consecutive cols
  {
    const int cl = tid & 31;
    const int pg = tid >> 5;  // [0,16)
    for (int it = 0; it < 136; ++it) {
      int p = it * 16 + pg;  // [0, 544*4)
      int k = p >> 2, g = p & 3;
      int col = g * HH + n0 + cl;
      float v = (k < DD) ? Wx[k * G4H + col] : Wh[(k - DD) * G4H + col];
      WlH[(g * 32 + cl) * 552 + k] = (_Float16)v;
    }
  }
  if (tid < 128) BiasS[tid] = bias[(tid >> 5) * HH + n0 + (tid & 31)];
  if (tid < 256) Cs[tid >> 5][tid & 31] = 0.f;

  _Float16* hb0 = (_Float16*)hws;  // fp16 h buffers
  _Float16* hb1 = (_Float16*)(hws + BB * HH);
  unsigned int* bar = (unsigned int*)(hws + 2 * BB * HH) + bb * 32;

  __syncthreads();  // WlH + BiasS ready

  // ---- hoist this wave's B-fragments into registers (persist 365 steps)
  f16x8 bfrag[17];
#pragma unroll
  for (int kk = 0; kk < 17; ++kk)
    bfrag[kk] = *(const f16x8*)&WlH[fcol * 552 + kk * 32 + kq * 8];
  const float bias_r = BiasS[fcol];

  // ---- stage x for t=0 (h0 = 0 from host memset)
  if (tid < 256) {
    int r = tid >> 5, c = tid & 31;
    AshH[r * 552 + c] = (_Float16)x[((size_t)(b0g + r) * TT + 0) * DD + c];
  }

  for (int t = 0; t < TT; ++t) {
    const _Float16* hprev = (t & 1) ? hb1 : hb0;
    _Float16* hnext = (t & 1) ? hb0 : hb1;

    // ---- per-wave poll: step t-1's producers all arrived?
    if (t > 0) {
      unsigned target = 16u * (unsigned)t;
      unsigned cur;
      do {
        unsigned v = 0;
        if (lane == 0)
          v = __hip_atomic_load(bar, __ATOMIC_RELAXED,
                                __HIP_MEMORY_SCOPE_AGENT);
        cur = (unsigned)__shfl((int)v, 0);
      } while (cur < target);
    }

    // ---- h loads: 2 agent-scope 8B atomic loads per thread (proven class)
    unsigned long long pre[2];
#pragma unroll
    for (int r = 0; r < 2; ++r) {
      int idx = r * 512 + tid;
      int rr = idx >> 7, kk = idx & 127;  // row, 4-half group
      pre[r] = __hip_atomic_load(
          (const unsigned long long*)(hprev + (size_t)(b0g + rr) * HH + kk * 4),
          __ATOMIC_RELAXED, __HIP_MEMORY_SCOPE_AGENT);
    }
#pragma unroll
    for (int r = 0; r < 2; ++r) {
      int idx = r * 512 + tid;
      int rr = idx >> 7, kk = idx & 127;
      *(unsigned long long*)&AshH[rr * 552 + DD + kk * 4] = pre[r];
    }
    __syncthreads();  // AshH ready (h now; x staged last iteration)

    // ---- MFMA: Z[16(8 valid) x 16] per wave, K=544, 2 indep accumulators
    f32x4 acc0 = {bias_r, bias_r, bias_r, bias_r};
    f32x4 acc1 = {0.f, 0.f, 0.f, 0.f};
#pragma unroll
    for (int kk = 0; kk < 17; ++kk) {
      f16x8 af;
      if (arow < 8) {
        af = *(const f16x8*)&AshH[arow * 552 + kk * 32 + kq * 8];
      } else {
        f16x8 z = {};
        af = z;
      }
      if (kk & 1)
        acc1 = __builtin_amdgcn_mfma_f32_16x16x32_f16(af, bfrag[kk], acc1, 0, 0, 0);
      else
        acc0 = __builtin_amdgcn_mfma_f32_16x16x32_f16(af, bfrag[kk], acc0, 0, 0, 0);
    }
    // C/D: col=lane&15 (-> fcol), row=(lane>>4)*4+r; rows 0..7 valid
    if (kq < 2) {
#pragma unroll
      for (int r = 0; r < 4; ++r)
        ZxS[(kq * 4 + r) * 128 + fcol] = acc0[r] + acc1[r];
    }
    __syncthreads();  // ZxS ready; AshH consumption done

    float hv = 0.f;
    int bg = 0, col = 0;
    if (tid < 256) {
      int b_l = tid >> 5, nn = tid & 31;
      float zi = ZxS[b_l * 128 + nn];
      float zf = ZxS[b_l * 128 + 32 + nn];
      float zg = ZxS[b_l * 128 + 64 + nn];
      float zo = ZxS[b_l * 128 + 96 + nn];
      float cnew = sigf(zf) * Cs[b_l][nn] + sigf(zi) * ftanh(zg);
      Cs[b_l][nn] = cnew;
      hv = sigf(zo) * ftanh(cnew);
      bg = b0g + b_l;
      col = n0 + nn;
      // ---- pack 4 consecutive cols into ONE 8B agent-scope atomic store
      int base = lane & ~3;
      float h0 = __shfl(hv, base + 0);
      float h1 = __shfl(hv, base + 1);
      float h2 = __shfl(hv, base + 2);
      float h3 = __shfl(hv, base + 3);
      if ((lane & 3) == 0) {
        union { unsigned long long u; _Float16 h[4]; } pk;
        pk.h[0] = (_Float16)h0;
        pk.h[1] = (_Float16)h1;
        pk.h[2] = (_Float16)h2;
        pk.h[3] = (_Float16)h3;
        __hip_atomic_store(
            (unsigned long long*)(hnext + (size_t)bg * HH + col), pk.u,
            __ATOMIC_RELAXED, __HIP_MEMORY_SCOPE_AGENT);
      }
    }
    // ---- stage x(t+1) into AshH x-region (MFMA reads of step t are done)
    if (t + 1 < TT && tid < 256) {
      int r = tid >> 5, c = tid & 31;
      AshH[r * 552 + c] =
          (_Float16)x[((size_t)(b0g + r) * TT + (t + 1)) * DD + c];
    }
    __syncthreads();  // drains vmcnt(0): h stores at coherence point

    if (tid == 0) {
      __hip_atomic_fetch_add(bar, 1u, __ATOMIC_RELAXED,
                             __HIP_MEMORY_SCOPE_AGENT);
    }
    if (tid < 256) {
      out[((size_t)bg * TT + t) * HH + col] = hv;  // in the poll shadow
    }
    // no trailing sync: next iteration's per-wave poll gates progress
  }
}

// ---------------------------------------------------------------------------
// Fallback: one launch per timestep (kernel-boundary coherence, fp32 h).
// Only used if the cooperative launch is rejected.
// ---------------------------------------------------------------------------
__global__ __launch_bounds__(256, 2)
void lstm_step(const float* __restrict__ x, const float* __restrict__ Wx,
               const float* __restrict__ Wh, const float* __restrict__ bias,
               float* __restrict__ out, const float* __restrict__ hprev,
               float* __restrict__ hnext, float* __restrict__ cst, int t) {
  __shared__ float Wl[16 * 544];
  __shared__ float Ash[32 * 128];
  __shared__ float Xs[32 * 32];
  __shared__ float Zx[4][32][4];
  __shared__ float BiasS[16];

  const int tid = threadIdx.x;
  const int ks = tid & 7;
  const int btile = (tid >> 3) & 7;
  const int ctile = tid >> 6;
  const int wg = blockIdx.x;
  const int bb = wg & 3;
  const int nb = wg >> 2;
  const int b0g = bb * 32;
  const int n0 = nb * 4;

  for (int idx = tid; idx < 16 * 544; idx += 256) {
    int zc = idx & 15, k = idx >> 4;
    int col = (zc >> 2) * HH + n0 + (zc & 3);
    Wl[zc * 544 + k] = (k < DD) ? Wx[k * G4H + col] : Wh[(k - DD) * G4H + col];
  }
  if (tid < 16) BiasS[tid] = bias[(tid >> 2) * HH + n0 + (tid & 3)];

  {
    int b_l = tid >> 3, kq = tid & 7;
    float4 v = *(const float4*)(x + ((size_t)(b0g + b_l) * TT + t) * DD + kq * 4);
    *(float4*)&Xs[b_l * 32 + kq * 4] = v;
  }

  float acc[4][4];
#pragma unroll
  for (int i = 0; i < 4; ++i)
#pragma unroll
    for (int c = 0; c < 4; ++c) acc[i][c] = 0.f;

  auto mac4 = [&](const float* Abase, int rstride, const float* Wbase) {
    float4 a4[4], w4[4];
#pragma unroll
    for (int i = 0; i < 4; ++i)
      a4[i] = *(const float4*)(Abase + (btile * 4 + i) * rstride);
#pragma unroll
    for (int c = 0; c < 4; ++c) w4[c] = *(const float4*)(Wbase + c * 544);
#pragma unroll
    for (int i = 0; i < 4; ++i)
#pragma unroll
      for (int c = 0; c < 4; ++c)
        acc[i][c] += a4[i].x * w4[c].x + a4[i].y * w4[c].y +
                     a4[i].z * w4[c].z + a4[i].w * w4[c].w;
  };

  for (int ch = 0; ch < 4; ++ch) {
    __syncthreads();
    for (int r = 0; r < 4; ++r) {
      int fidx = r * 256 + tid;
      int b_l = fidx >> 5, kq = fidx & 31;
      float4 v = *(const float4*)(hprev + (size_t)(b0g + b_l) * HH + ch * 128 +
                                  kq * 4);
      *(float4*)&Ash[b_l * 128 + kq * 4] = v;
    }
    __syncthreads();
    if (ch == 0) mac4(&Xs[ks * 4], 32, &Wl[(ctile * 4) * 544 + ks * 4]);
#pragma unroll
    for (int j = 0; j < 4; ++j)
      mac4(&Ash[j * 32 + ks * 4], 128,
           &Wl[(ctile * 4) * 544 + DD + ch * 128 + j * 32 + ks * 4]);
  }

#pragma unroll
  for (int i = 0; i < 4; ++i)
#pragma unroll
    for (int c = 0; c < 4; ++c) {
      float v = acc[i][c];
      v += __shfl_xor(v, 1);
      v += __shfl_xor(v, 2);
      v += __shfl_xor(v, 4);
      acc[i][c] = v;
    }

  if (ks == 0) {
#pragma unroll
    for (int i = 0; i < 4; ++i)
#pragma unroll
      for (int c = 0; c < 4; ++c)
        Zx[ctile][btile * 4 + i][c] = acc[i][c] + BiasS[ctile * 4 + c];
  }
  __syncthreads();

  if (tid < 128) {
    int b_l = tid >> 2, nn = tid & 3;
    float zi = Zx[0][b_l][nn], zf = Zx[1][b_l][nn];
    float zg = Zx[2][b_l][nn], zo = Zx[3][b_l][nn];
    int bg = b0g + b_l, col = n0 + nn;
    size_t cidx = (size_t)bg * HH + col;
    float cnew = sigf(zf) * cst[cidx] + sigf(zi) * tanhf(zg);
    cst[cidx] = cnew;
    float hv = sigf(zo) * tanhf(cnew);
    hnext[cidx] = hv;
    out[((size_t)bg * TT + t) * HH + col] = hv;
  }
}

extern "C" void kernel_launch(void* const* d_in, const int* in_sizes, int n_in,
                              void* d_out, int out_size, void* d_ws, size_t ws_size,
                              hipStream_t stream) {
  const float* x = (const float*)d_in[0];
  const float* Wx = (const float*)d_in[1];
  const float* Wh = (const float*)d_in[2];
  const float* bv = (const float*)d_in[3];
  float* out = (float*)d_out;
  float* hws = (float*)d_ws;

  // zero: buf0 | buf1 | barrier counters | cst = (3*65536 + 256) * 4 bytes
  hipMemsetAsync(d_ws, 0, (size_t)(3 * 65536 + 256) * 4, stream);

  void* args[] = {(void*)&x, (void*)&Wx, (void*)&Wh,
                  (void*)&bv, (void*)&out, (void*)&hws};
  hipError_t err = hipLaunchCooperativeKernel(
      reinterpret_cast<void*>(lstm_persistent), dim3(256), dim3(512), args, 0,
      stream);
  if (err != hipSuccess) {
    (void)hipGetLastError();
    float* buf0 = hws;
    float* buf1 = hws + BB * HH;
    float* cst = hws + 2 * BB * HH + 256;
    for (int t = 0; t < TT; ++t) {
      const float* hp = (t & 1) ? buf1 : buf0;
      float* hn = (t & 1) ? buf0 : buf1;
      lstm_step<<<dim3(512), dim3(256), 0, stream>>>(x, Wx, Wh, bv, out, hp, hn,
                                                     cst, t);
    }
  }
}